// Round 21
// baseline (8325.468 us; speedup 1.0000x reference)
//
#include <hip/hip_runtime.h>
#include <cstdint>

typedef __attribute__((ext_vector_type(8))) short short8;   // 8 bf16 in 4 VGPRs
typedef __attribute__((ext_vector_type(4))) float floatx4;
typedef __attribute__((ext_vector_type(2))) unsigned long long u64x2;

typedef unsigned short u16;
typedef unsigned int u32;
typedef unsigned long long u64;

template<int N> struct IC { static constexpr int v = N; };

__device__ __forceinline__ u16 f2bf(float x) {
    u32 u = __builtin_bit_cast(u32, x);
    u32 r = (u + 0x7fffu + ((u >> 16) & 1u)) >> 16;
    return (u16)r;
}
__device__ __forceinline__ float bf2f(u16 u) {
    return __builtin_bit_cast(float, (u32)u << 16);
}

__device__ __forceinline__ void gload_lds16(const void* g, void* l) {
    __builtin_amdgcn_global_load_lds(
        (const __attribute__((address_space(1))) void*)g,
        (__attribute__((address_space(3))) void*)l, 16, 0, 0);
}

// ---------------- f32 -> bf16 convert (x input, once) ------------------------
__global__ __launch_bounds__(256) void cvt_f32_bf16(const float* __restrict__ src,
                                                    u16* __restrict__ dst, long n) {
    long i = ((long)blockIdx.x * 256 + threadIdx.x) * 8;
    if (i >= n) return;
    float4 a = *(const float4*)(src + i);
    float4 b = *(const float4*)(src + i + 4);
    short8 o;
    o[0] = (short)f2bf(a.x); o[1] = (short)f2bf(a.y);
    o[2] = (short)f2bf(a.z); o[3] = (short)f2bf(a.w);
    o[4] = (short)f2bf(b.x); o[5] = (short)f2bf(b.y);
    o[6] = (short)f2bf(b.z); o[7] = (short)f2bf(b.w);
    *(short8*)(dst + i) = o;
}

// ---------------- per-layer prep: cvt w_ih + cvt w_hh + h_init + zero SYNC ---
__global__ __launch_bounds__(256) void prep_layer(const float* __restrict__ wih_l,
                                                  u16* __restrict__ WIH,
                                                  const float* __restrict__ whh_l,
                                                  u16* __restrict__ WHH,
                                                  const float* __restrict__ h0l,
                                                  u16* __restrict__ H16G,
                                                  int* __restrict__ SYNC) {
    const int bid = blockIdx.x;
    if (bid < 6144) {
        long i = ((long)bid * 256 + threadIdx.x) * 8;
        float4 a = *(const float4*)(wih_l + i);
        float4 b = *(const float4*)(wih_l + i + 4);
        short8 o;
        o[0] = (short)f2bf(a.x); o[1] = (short)f2bf(a.y);
        o[2] = (short)f2bf(a.z); o[3] = (short)f2bf(a.w);
        o[4] = (short)f2bf(b.x); o[5] = (short)f2bf(b.y);
        o[6] = (short)f2bf(b.z); o[7] = (short)f2bf(b.w);
        *(short8*)(WIH + i) = o;
    } else if (bid < 9216) {
        long i = ((long)(bid - 6144) * 256 + threadIdx.x) * 8;
        float4 a = *(const float4*)(whh_l + i);
        float4 b = *(const float4*)(whh_l + i + 4);
        short8 o;
        o[0] = (short)f2bf(a.x); o[1] = (short)f2bf(a.y);
        o[2] = (short)f2bf(a.z); o[3] = (short)f2bf(a.w);
        o[4] = (short)f2bf(b.x); o[5] = (short)f2bf(b.y);
        o[6] = (short)f2bf(b.z); o[7] = (short)f2bf(b.w);
        *(short8*)(WHH + i) = o;
    } else if (bid < 9728) {
        int idx = (bid - 9216) * 256 + threadIdx.x;   // 0..131071
        int d = idx >> 16;
        int r = idx & 65535;
        int b = r >> 10;
        int j = r & 1023;
        float v = h0l[(long)d * 65536 + r];
        H16G[(long)(d * 4 + (b >> 4)) * 16384 + (b & 15) * 1024 + j] = f2bf(v);
    } else {
        int idx = (bid - 9728) * 256 + threadIdx.x;   // 0..8703
        __hip_atomic_store(&SYNC[idx], 0, __ATOMIC_RELAXED, __HIP_MEMORY_SCOPE_AGENT);
    }
}

// ---------------- input-projection GEMM --------------------------------------
template<int BLOCKED_A>
__global__ __launch_bounds__(256) void gemm_bt_bf16(const u16* __restrict__ A,
                                                    const u16* __restrict__ B,
                                                    u16* __restrict__ C) {
    __shared__ u16 As[128 * 64];
    __shared__ u16 Bs[128 * 64];
    const int tid = threadIdx.x;
    const int w = tid >> 6, l = tid & 63;
    const int m0 = blockIdx.y * 128;
    const int n0 = blockIdx.x * 128;
    const int wr = w >> 1, wc = w & 1;

    floatx4 acc[4][4] = {};

    const int lr = tid >> 3;
    const int ch = tid & 7;
    long bA[4];
#pragma unroll
    for (int c = 0; c < 4; ++c) {
        const int m = m0 + lr + 32 * c;
        if (BLOCKED_A)
            bA[c] = (long)(ch >> 1) * 262144 + (m >> 6) * 1024 + (m & 63) * 16 + (ch & 1) * 8;
        else
            bA[c] = (long)m * 2048 + ch * 8;
    }
    const long kstride = BLOCKED_A ? 1048576 : 64;
    const u16* gB = B + (long)(n0 + lr) * 2048 + ch * 8;

    for (int kt = 0; kt < 32; ++kt) {
#pragma unroll
        for (int c = 0; c < 4; ++c)
            gload_lds16(A + bA[c] + kt * kstride, &As[c * 2048 + tid * 8]);
#pragma unroll
        for (int c = 0; c < 4; ++c)
            gload_lds16(gB + (long)c * 65536 + kt * 64, &Bs[c * 2048 + tid * 8]);
        __syncthreads();
#pragma unroll
        for (int ks = 0; ks < 2; ++ks) {
            short8 af[4], bfr[4];
#pragma unroll
            for (int mt = 0; mt < 4; ++mt)
                af[mt] = *(const short8*)&As[(wr * 64 + mt * 16 + (l & 15)) * 64 + ks * 32 + (l >> 4) * 8];
#pragma unroll
            for (int nt = 0; nt < 4; ++nt)
                bfr[nt] = *(const short8*)&Bs[(wc * 64 + nt * 16 + (l & 15)) * 64 + ks * 32 + (l >> 4) * 8];
#pragma unroll
            for (int mt = 0; mt < 4; ++mt)
#pragma unroll
                for (int nt = 0; nt < 4; ++nt)
                    acc[mt][nt] = __builtin_amdgcn_mfma_f32_16x16x32_bf16(af[mt], bfr[nt], acc[mt][nt], 0, 0, 0);
        }
        __syncthreads();
    }
    const int t_row = blockIdx.y * 2 + wr;
#pragma unroll
    for (int nt = 0; nt < 4; ++nt) {
        const int col = n0 + wc * 64 + nt * 16 + (l & 15);
        const int dir = col / 3072;
        const int rem = col - dir * 3072;
        const int gate = rem >> 10;
        const int j = rem & 1023;
        const int base = (((dir * 64 + (j >> 4)) * 256 + t_row) * 64) * 48 + gate * 16 + (j & 15);
#pragma unroll
        for (int mt = 0; mt < 4; ++mt)
#pragma unroll
            for (int i = 0; i < 4; ++i) {
                const int b = mt * 16 + (l >> 4) * 4 + i;
                C[base + b * 48] = f2bf(acc[mt][nt][i]);
            }
    }
}

// ---------------- persistent GRU scan (one launch per layer) -----------------
// R17 sync structure with HALVED participants: 16 blocks x 1024 threads per
// group (64 j-cols/block, 16 waves = (jg 0..3, kw 0..3); per-wave work
// identical to R17). 256 blocks launched, 1/CU (LDS 82944B) -> exactly 32/XCD;
// 16 claim the XCD's group, 16 exit. Flags: 16/group, wave-0 poll (proven).
__global__ __launch_bounds__(1024, 1) void gru_scan(const u16* __restrict__ WHH,  // [6144][1024]
                                                    const u16* __restrict__ GIn,  // scan-blocked
                                                    const float* __restrict__ bih,
                                                    const float* __restrict__ bhh,
                                                    const float* __restrict__ h0l, // [2][64][1024]
                                                    u16* H16G,        // [2p][8g][16b][1024j]
                                                    u16* Ybf,         // layer<2: blocked out
                                                    float* Yf32,      // layer==2: rowmajor f32
                                                    int* flags) {
    __shared__ float P[4][4][3][16][20];     // [jg][kw][gate][j16][b pad20] = 60KB
    __shared__ float lds_pad[5376];          // pad to 82944B -> 1 block/CU
    __shared__ int sh_role, sh_fast;
    const int tid = threadIdx.x;

    int* ctl = flags + 8192;
    if (tid == 0) {
        u32 xcc;
        asm volatile("s_getreg_b32 %0, hwreg(HW_REG_XCC_ID)" : "=s"(xcc));
        xcc &= 7u;
        int r = __hip_atomic_fetch_add(&ctl[(int)xcc], 1, __ATOMIC_RELAXED, __HIP_MEMORY_SCOPE_AGENT);
        int role = (r < 16) ? ((int)xcc * 16 + r) : -1;
        __hip_atomic_fetch_add(&ctl[8], 1, __ATOMIC_ACQ_REL, __HIP_MEMORY_SCOPE_AGENT);
        while (__hip_atomic_load(&ctl[8], __ATOMIC_ACQUIRE, __HIP_MEMORY_SCOPE_AGENT) < 256)
            __builtin_amdgcn_s_sleep(8);
        if (role < 0) {   // rescue: deterministically fill unclaimed slots
            int f[8];
            for (int x = 0; x < 8; ++x) {
                int v = __hip_atomic_load(&ctl[x], __ATOMIC_RELAXED, __HIP_MEMORY_SCOPE_AGENT);
                f[x] = v > 16 ? 16 : v;
            }
            int r2 = __hip_atomic_fetch_add(&ctl[9], 1, __ATOMIC_RELAXED, __HIP_MEMORY_SCOPE_AGENT);
            int cum = 0;
            for (int x = 0; x < 8; ++x) {
                const int d = 16 - f[x];
                if (role < 0 && r2 < cum + d) role = x * 16 + f[x] + (r2 - cum);
                cum += d;
            }
        }
        int fast = 0;
        if (role >= 0) {
            const int g = role >> 4;
            __hip_atomic_store(&ctl[32 + role], (int)xcc, __ATOMIC_RELAXED, __HIP_MEMORY_SCOPE_AGENT);
            __hip_atomic_fetch_add(&ctl[16 + g], 1, __ATOMIC_ACQ_REL, __HIP_MEMORY_SCOPE_AGENT);
            while (__hip_atomic_load(&ctl[16 + g], __ATOMIC_ACQUIRE, __HIP_MEMORY_SCOPE_AGENT) < 16)
                __builtin_amdgcn_s_sleep(8);
            fast = 1;
            for (int k = 0; k < 16; ++k)
                if (__hip_atomic_load(&ctl[32 + g * 16 + k], __ATOMIC_RELAXED, __HIP_MEMORY_SCOPE_AGENT) != (int)xcc)
                    fast = 0;
        }
        sh_role = role;
        sh_fast = fast;
    }
    __syncthreads();
    const int role = sh_role;
    if (role < 0) return;                    // surplus blocks exit
    const int fastv = sh_fast;
    if (fastv == 2) ((volatile float*)lds_pad)[tid & 1023] = 0.f;   // keep pad

    const int w = tid >> 6, l = tid & 63;
    const int jg = w >> 2;       // j quarter 0..3 (16 cols each)
    const int kw = w & 3;        // K-slice 0..3
    const int g = role >> 4;     // group = (dir, bh)
    const int jc2 = role & 15;   // 16 blocks/group, 64 j-cols each
    const int dir = g >> 2;
    const int bh = g & 3;
    const int lrow = l & 15;
    const int lhi = l >> 4;      // 0..3

    int* gflags = flags + g * 1024;   // 16 flags, stride 32 ints

    // w_hh fragments: rows = this block's 64 j-cols, K slice [kw*256,+256)
    const int jd = jc2 * 64 + jg * 16 + lrow;    // j within dir (0..1023)
    const int jb = jc2 * 4 + jg;                 // 16-col group id (0..63)
    const u16* wbase = WHH + (long)dir * 3072 * 1024;
    short8 breg[3][8];
#pragma unroll
    for (int nt = 0; nt < 3; ++nt) {
        const long row = nt * 1024 + jd;
#pragma unroll
        for (int kk = 0; kk < 8; ++kk)
            breg[nt][kk] = *(const short8*)&wbase[row * 1024 + (kw * 8 + kk) * 32 + lhi * 8];
    }

    const float bihR = bih[dir * 3072 + jd];
    const float bihZ = bih[dir * 3072 + 1024 + jd];
    const float bihN = bih[dir * 3072 + 2048 + jd];
    const float bhhR = bhh[dir * 3072 + jd];
    const float bhhZ = bhh[dir * 3072 + 1024 + jd];
    const float bhhN = bhh[dir * 3072 + 2048 + jd];

    // this thread's single output: b_loc = kw*4 + lhi, j = jd
    const int b_loc = kw * 4 + lhi;
    const int b_glob = bh * 16 + b_loc;
    float hreg = h0l[dir * 65536 + b_glob * 1024 + jd];

    const u16* gib = GIn + (long)(dir * 64 + jb) * 256 * 3072 + b_glob * 48 + lrow;

    // prologue: GI gate inputs for step 0
    u16 givR, givZ, givN;
    {
        const long toff = (long)(dir ? 255 : 0) * 3072;
        givR = __builtin_nontemporal_load(gib + toff);
        givZ = __builtin_nontemporal_load(gib + toff + 16);
        givN = __builtin_nontemporal_load(gib + toff + 32);
    }

#define LOADH(DST, KK)                                                          \
        {                                                                       \
            const u16* p = hb16 + lrow * 1024 + kw * 256 + (KK) * 32 + lhi * 8; \
            if constexpr (FAST) {                                               \
                DST = *(const short8*)p;                                        \
            } else {                                                            \
                const u64* q8 = (const u64*)p;                                  \
                u64x2 q;                                                        \
                q[0] = __hip_atomic_load(q8,     __ATOMIC_RELAXED, __HIP_MEMORY_SCOPE_AGENT); \
                q[1] = __hip_atomic_load(q8 + 1, __ATOMIC_RELAXED, __HIP_MEMORY_SCOPE_AGENT); \
                DST = __builtin_bit_cast(short8, q);                            \
            }                                                                   \
        }
#define MFMA3(SRC, KK)                                                          \
        {                                                                       \
            _Pragma("unroll")                                                   \
            for (int nt = 0; nt < 3; ++nt)                                      \
                acc[nt] = __builtin_amdgcn_mfma_f32_16x16x32_bf16(              \
                    SRC, breg[nt][KK], acc[nt], 0, 0, 0);                       \
        }

    auto body = [&](auto fc) {
        constexpr int FAST = decltype(fc)::v;
        for (int s = 0; s < 256; ++s) {
            const int parity = s & 1;
            const int t_eff = dir ? (255 - s) : s;
            if constexpr (FAST) {
                asm volatile("buffer_inv sc0" ::: "memory");   // L1 acquire
            }
            const u16* hb16 = H16G + (long)(parity * 8 + g) * 16384;

            short8 afX, afY, afZ, afW;
            floatx4 acc[3] = {};
            LOADH(afX, 0)
            LOADH(afY, 1)
            LOADH(afZ, 2)
            LOADH(afW, 3)

            // GI prefetch for NEXT step, issued during compute (R17 ordering)
            u16 gnR = 0, gnZ = 0, gnN = 0;
            if (s < 255) {
                const long toff = (long)(dir ? (254 - s) : (s + 1)) * 3072;
                gnR = __builtin_nontemporal_load(gib + toff);
                gnZ = __builtin_nontemporal_load(gib + toff + 16);
                gnN = __builtin_nontemporal_load(gib + toff + 32);
            }

            MFMA3(afX, 0) LOADH(afX, 4)
            MFMA3(afY, 1) LOADH(afY, 5)
            MFMA3(afZ, 2) LOADH(afZ, 6)
            MFMA3(afW, 3) LOADH(afW, 7)
            MFMA3(afX, 4)
            MFMA3(afY, 5)
            MFMA3(afZ, 6)
            MFMA3(afW, 7)

            // partials -> LDS: D row = b_local, col = j
#pragma unroll
            for (int nt = 0; nt < 3; ++nt)
                *(floatx4*)&P[jg][kw][nt][lrow][lhi * 4] = acc[nt];
            asm volatile("s_waitcnt lgkmcnt(0)" ::: "memory");
            __builtin_amdgcn_sched_barrier(0);
            __builtin_amdgcn_s_barrier();                  // B1: LDS only
            __builtin_amdgcn_sched_barrier(0);

            // reduce over kw partials for this thread's (j = jd, b = b_loc)
            float sR = 0.f, sZ = 0.f, sN = 0.f;
#pragma unroll
            for (int wp = 0; wp < 4; ++wp) {
                sR += P[jg][wp][0][lrow][b_loc];
                sZ += P[jg][wp][1][lrow][b_loc];
                sN += P[jg][wp][2][lrow][b_loc];
            }
            const float xr = bf2f(givR) + bihR + sR + bhhR;
            const float xz = bf2f(givZ) + bihZ + sZ + bhhZ;
            const float rg = 1.f / (1.f + __expf(-xr));
            const float zg = 1.f / (1.f + __expf(-xz));
            float xn = bf2f(givN) + bihN + rg * (sN + bhhN);
            xn = fminf(fmaxf(xn, -20.f), 20.f);
            const float e2 = __expf(-2.f * xn);
            const float ng = (1.f - e2) / (1.f + e2);
            const float hnew = (1.f - zg) * ng + zg * hreg;
            hreg = hnew;

            // stores: H16 first, then Y (both plain in FAST -> L2 ack)
            __builtin_amdgcn_sched_barrier(0);
            {
                u16* hp = H16G + (long)((parity ^ 1) * 8 + g) * 16384 + b_loc * 1024 + jd;
                if constexpr (FAST) *hp = f2bf(hnew);
                else __hip_atomic_store(hp, f2bf(hnew), __ATOMIC_RELAXED, __HIP_MEMORY_SCOPE_AGENT);
            }
            __builtin_amdgcn_sched_barrier(0);
            if (Yf32) {
                Yf32[(long)(t_eff * 64 + b_glob) * 2048 + dir * 1024 + jd] = hnew;
            } else {
                Ybf[((long)(dir * 64 + jb) * 256 + t_eff) * 1024 + b_glob * 16 + lrow] = f2bf(hnew);
            }
            __builtin_amdgcn_sched_barrier(0);
            asm volatile("s_waitcnt vmcnt(1)" ::: "memory");   // H16 acked
            __builtin_amdgcn_sched_barrier(0);
            __builtin_amdgcn_s_barrier();                  // B2: block's H16 visible
            if (tid == 0) {
                if constexpr (FAST) ((volatile int*)gflags)[jc2 * 32] = s + 1;
                else __hip_atomic_store(&gflags[jc2 * 32], s + 1, __ATOMIC_RELAXED, __HIP_MEMORY_SCOPE_AGENT);
            }

            // poll (wave 0 only; proven buffer_inv + volatile sequence)
            if (w == 0) {
                if constexpr (FAST) {
                    while (true) {
                        asm volatile("buffer_inv sc0" ::: "memory");
                        int v = ((volatile int*)gflags)[(l & 15) * 32];
                        if (v >= s + 1) break;
                        __builtin_amdgcn_s_sleep(1);
                    }
                } else {
                    while (__hip_atomic_load(&gflags[(l & 15) * 32], __ATOMIC_RELAXED, __HIP_MEMORY_SCOPE_AGENT) < s + 1)
                        __builtin_amdgcn_s_sleep(1);
                }
            }
            __builtin_amdgcn_sched_barrier(0);
            __builtin_amdgcn_s_barrier();                  // B3: release block
            __builtin_amdgcn_sched_barrier(0);

            givR = gnR; givZ = gnZ; givN = gnN;
        }
    };
    if (fastv) body(IC<1>{});
    else       body(IC<0>{});
#undef LOADH
#undef MFMA3
}

// ---------------- launch ------------------------------------------------------
extern "C" void kernel_launch(void* const* d_in, const int* in_sizes, int n_in,
                              void* d_out, int out_size, void* d_ws, size_t ws_size,
                              hipStream_t stream) {
    const float* x    = (const float*)d_in[0];
    const float* h0   = (const float*)d_in[1];
    const float* w_ih = (const float*)d_in[2];   // [3][2][3072][2048]
    const float* w_hh = (const float*)d_in[3];   // [3][2][3072][1024]
    const float* b_ih = (const float*)d_in[4];   // [3][2][3072]
    const float* b_hh = (const float*)d_in[5];
    float* out = (float*)d_out;

    char* ws = (char*)d_ws;
    u16*   XB0 = (u16*)(ws);                      //  64 MiB
    u16*   XB1 = (u16*)(ws + 67108864);           //  64 MiB
    u16*   GI  = (u16*)(ws + 134217728);          // 192 MiB scan-blocked bf16
    u16*   WIH = (u16*)(ws + 335544320);          //  24 MiB
    u16*   WHH = (u16*)(ws + 360710144);          //  12 MiB
    int*   SYNC = (int*)(ws + 373293056);         //  34 KiB flags+ctl (own region)
    u16*   H16 = (u16*)(ws + 374341632);          // 512 KiB group layout [2][8][16][1024]

    cvt_f32_bf16<<<16384, 256, 0, stream>>>(x, XB0, 33554432L);

    for (int layer = 0; layer < 3; ++layer) {
        const u16* xin = (layer == 1) ? XB1 : XB0;
        u16* yout = (layer == 0) ? XB1 : ((layer == 1) ? XB0 : nullptr);

        prep_layer<<<9762, 256, 0, stream>>>(w_ih + (long)layer * 12582912, WIH,
                                             w_hh + (long)layer * 6291456, WHH,
                                             h0 + (long)(2 * layer) * 65536, H16, SYNC);

        dim3 g(48, 128);
        if (layer == 0)
            gemm_bt_bf16<0><<<g, 256, 0, stream>>>(xin, WIH, GI);
        else
            gemm_bt_bf16<1><<<g, 256, 0, stream>>>(xin, WIH, GI);

        const float* bihl = b_ih + (long)layer * 6144;
        const float* bhhl = b_hh + (long)layer * 6144;
        gru_scan<<<256, 1024, 0, stream>>>(WHH, GI, bihl, bhhl,
                                           h0 + (long)(2 * layer) * 65536, H16,
                                           yout, (layer == 2) ? out : nullptr, SYNC);
    }
}

// Round 22
// 3994.024 us; speedup vs baseline: 2.0845x; 2.0845x over previous
//
#include <hip/hip_runtime.h>
#include <cstdint>

typedef __attribute__((ext_vector_type(8))) short short8;   // 8 bf16 in 4 VGPRs
typedef __attribute__((ext_vector_type(4))) float floatx4;
typedef __attribute__((ext_vector_type(2))) unsigned long long u64x2;

typedef unsigned short u16;
typedef unsigned int u32;
typedef unsigned long long u64;

template<int N> struct IC { static constexpr int v = N; };

__device__ __forceinline__ u16 f2bf(float x) {
    u32 u = __builtin_bit_cast(u32, x);
    u32 r = (u + 0x7fffu + ((u >> 16) & 1u)) >> 16;
    return (u16)r;
}
__device__ __forceinline__ float bf2f(u16 u) {
    return __builtin_bit_cast(float, (u32)u << 16);
}

__device__ __forceinline__ void gload_lds16(const void* g, void* l) {
    __builtin_amdgcn_global_load_lds(
        (const __attribute__((address_space(1))) void*)g,
        (__attribute__((address_space(3))) void*)l, 16, 0, 0);
}

// ---------------- f32 -> bf16 convert (x input, once) ------------------------
__global__ __launch_bounds__(256) void cvt_f32_bf16(const float* __restrict__ src,
                                                    u16* __restrict__ dst, long n) {
    long i = ((long)blockIdx.x * 256 + threadIdx.x) * 8;
    if (i >= n) return;
    float4 a = *(const float4*)(src + i);
    float4 b = *(const float4*)(src + i + 4);
    short8 o;
    o[0] = (short)f2bf(a.x); o[1] = (short)f2bf(a.y);
    o[2] = (short)f2bf(a.z); o[3] = (short)f2bf(a.w);
    o[4] = (short)f2bf(b.x); o[5] = (short)f2bf(b.y);
    o[6] = (short)f2bf(b.z); o[7] = (short)f2bf(b.w);
    *(short8*)(dst + i) = o;
}

// ---------------- per-layer prep: cvt w_ih + cvt w_hh + h_init + zero SYNC ---
// 9762 blocks x 256: [0,6144) wih cvt, [6144,9216) whh cvt, [9216,9728) h_init,
// [9728,9762) zero 8704 SYNC ints. All four regions disjoint.
__global__ __launch_bounds__(256) void prep_layer(const float* __restrict__ wih_l,
                                                  u16* __restrict__ WIH,
                                                  const float* __restrict__ whh_l,
                                                  u16* __restrict__ WHH,
                                                  const float* __restrict__ h0l,
                                                  u16* __restrict__ H16G,
                                                  int* __restrict__ SYNC) {
    const int bid = blockIdx.x;
    if (bid < 6144) {
        long i = ((long)bid * 256 + threadIdx.x) * 8;
        float4 a = *(const float4*)(wih_l + i);
        float4 b = *(const float4*)(wih_l + i + 4);
        short8 o;
        o[0] = (short)f2bf(a.x); o[1] = (short)f2bf(a.y);
        o[2] = (short)f2bf(a.z); o[3] = (short)f2bf(a.w);
        o[4] = (short)f2bf(b.x); o[5] = (short)f2bf(b.y);
        o[6] = (short)f2bf(b.z); o[7] = (short)f2bf(b.w);
        *(short8*)(WIH + i) = o;
    } else if (bid < 9216) {
        long i = ((long)(bid - 6144) * 256 + threadIdx.x) * 8;
        float4 a = *(const float4*)(whh_l + i);
        float4 b = *(const float4*)(whh_l + i + 4);
        short8 o;
        o[0] = (short)f2bf(a.x); o[1] = (short)f2bf(a.y);
        o[2] = (short)f2bf(a.z); o[3] = (short)f2bf(a.w);
        o[4] = (short)f2bf(b.x); o[5] = (short)f2bf(b.y);
        o[6] = (short)f2bf(b.z); o[7] = (short)f2bf(b.w);
        *(short8*)(WHH + i) = o;
    } else if (bid < 9728) {
        int idx = (bid - 9216) * 256 + threadIdx.x;   // 0..131071
        int d = idx >> 16;
        int r = idx & 65535;
        int b = r >> 10;
        int j = r & 1023;
        float v = h0l[(long)d * 65536 + r];
        H16G[(long)(d * 4 + (b >> 4)) * 16384 + (b & 15) * 1024 + j] = f2bf(v);
    } else {
        int idx = (bid - 9728) * 256 + threadIdx.x;   // 0..8703
        __hip_atomic_store(&SYNC[idx], 0, __ATOMIC_RELAXED, __HIP_MEMORY_SCOPE_AGENT);
    }
}

// ---------------- input-projection GEMM --------------------------------------
// A: rowmajor [16384][2048] (BLOCKED_A=0) or scan-blocked [2d][64jb][256t][64b][16]
// (BLOCKED_A=1; offset(m,k) = (k>>4)*262144 + (m>>6)*1024 + (m&63)*16 + (k&15)).
// B: WIH rowmajor [6144][2048]. C: scan-blocked GI.
template<int BLOCKED_A>
__global__ __launch_bounds__(256) void gemm_bt_bf16(const u16* __restrict__ A,
                                                    const u16* __restrict__ B,
                                                    u16* __restrict__ C) {
    __shared__ u16 As[128 * 64];
    __shared__ u16 Bs[128 * 64];
    const int tid = threadIdx.x;
    const int w = tid >> 6, l = tid & 63;
    const int m0 = blockIdx.y * 128;
    const int n0 = blockIdx.x * 128;
    const int wr = w >> 1, wc = w & 1;

    floatx4 acc[4][4] = {};

    const int lr = tid >> 3;
    const int ch = tid & 7;
    long bA[4];
#pragma unroll
    for (int c = 0; c < 4; ++c) {
        const int m = m0 + lr + 32 * c;
        if (BLOCKED_A)
            bA[c] = (long)(ch >> 1) * 262144 + (m >> 6) * 1024 + (m & 63) * 16 + (ch & 1) * 8;
        else
            bA[c] = (long)m * 2048 + ch * 8;
    }
    const long kstride = BLOCKED_A ? 1048576 : 64;
    const u16* gB = B + (long)(n0 + lr) * 2048 + ch * 8;

    for (int kt = 0; kt < 32; ++kt) {
#pragma unroll
        for (int c = 0; c < 4; ++c)
            gload_lds16(A + bA[c] + kt * kstride, &As[c * 2048 + tid * 8]);
#pragma unroll
        for (int c = 0; c < 4; ++c)
            gload_lds16(gB + (long)c * 65536 + kt * 64, &Bs[c * 2048 + tid * 8]);
        __syncthreads();
#pragma unroll
        for (int ks = 0; ks < 2; ++ks) {
            short8 af[4], bfr[4];
#pragma unroll
            for (int mt = 0; mt < 4; ++mt)
                af[mt] = *(const short8*)&As[(wr * 64 + mt * 16 + (l & 15)) * 64 + ks * 32 + (l >> 4) * 8];
#pragma unroll
            for (int nt = 0; nt < 4; ++nt)
                bfr[nt] = *(const short8*)&Bs[(wc * 64 + nt * 16 + (l & 15)) * 64 + ks * 32 + (l >> 4) * 8];
#pragma unroll
            for (int mt = 0; mt < 4; ++mt)
#pragma unroll
                for (int nt = 0; nt < 4; ++nt)
                    acc[mt][nt] = __builtin_amdgcn_mfma_f32_16x16x32_bf16(af[mt], bfr[nt], acc[mt][nt], 0, 0, 0);
        }
        __syncthreads();
    }
    const int t_row = blockIdx.y * 2 + wr;
#pragma unroll
    for (int nt = 0; nt < 4; ++nt) {
        const int col = n0 + wc * 64 + nt * 16 + (l & 15);
        const int dir = col / 3072;
        const int rem = col - dir * 3072;
        const int gate = rem >> 10;
        const int j = rem & 1023;
        const int base = (((dir * 64 + (j >> 4)) * 256 + t_row) * 64) * 48 + gate * 16 + (j & 15);
#pragma unroll
        for (int mt = 0; mt < 4; ++mt)
#pragma unroll
            for (int i = 0; i < 4; ++i) {
                const int b = mt * 16 + (l >> 4) * 4 + i;
                C[base + b * 48] = f2bf(acc[mt][nt][i]);
            }
    }
}

// ---------------- persistent GRU scan (one launch per layer) -----------------
// R17/R20 measured-optimal structure. 8 independent groups g=(dir,bh), 1 per
// XCD (1 block/CU forced by LDS). Block = 32 j-cols; wave (jg,kw).
// Per-step: buffer_inv .. h-loads + early GI prefetch + MFMA .. B1 (LDS) ..
// gates .. H16 + Y plain stores .. vmcnt(1) .. B2 .. tid0 post .. wave-0 poll
// (proven buffer_inv + volatile) .. B3.
__global__ __launch_bounds__(512, 1) void gru_scan(const u16* __restrict__ WHH,  // [6144][1024]
                                                   const u16* __restrict__ GIn,  // scan-blocked
                                                   const float* __restrict__ bih,
                                                   const float* __restrict__ bhh,
                                                   const float* __restrict__ h0l, // [2][64][1024]
                                                   u16* H16G,        // [2p][8g][16b][1024j]
                                                   u16* Ybf,         // layer<2: blocked out
                                                   float* Yf32,      // layer==2: rowmajor f32
                                                   int* flags) {
    __shared__ float P[2][4][4][3][16][20];  // [jg][kw][0][gate][j16][b pad20]
    __shared__ int sh_role, sh_fast;
    const int tid = threadIdx.x;

    int* ctl = flags + 8192;
    if (tid == 0) {
        u32 xcc;
        asm volatile("s_getreg_b32 %0, hwreg(HW_REG_XCC_ID)" : "=s"(xcc));
        xcc &= 7u;
        int r = __hip_atomic_fetch_add(&ctl[(int)xcc], 1, __ATOMIC_RELAXED, __HIP_MEMORY_SCOPE_AGENT);
        int role = (r < 32) ? ((int)xcc * 32 + r) : -1;
        __hip_atomic_fetch_add(&ctl[8], 1, __ATOMIC_ACQ_REL, __HIP_MEMORY_SCOPE_AGENT);
        while (__hip_atomic_load(&ctl[8], __ATOMIC_ACQUIRE, __HIP_MEMORY_SCOPE_AGENT) < 256)
            __builtin_amdgcn_s_sleep(8);
        if (role < 0) {   // rescue: deterministically fill unclaimed slots
            int f[8];
            for (int x = 0; x < 8; ++x) {
                int v = __hip_atomic_load(&ctl[x], __ATOMIC_RELAXED, __HIP_MEMORY_SCOPE_AGENT);
                f[x] = v > 32 ? 32 : v;
            }
            int r2 = __hip_atomic_fetch_add(&ctl[9], 1, __ATOMIC_RELAXED, __HIP_MEMORY_SCOPE_AGENT);
            int cum = 0;
            for (int x = 0; x < 8; ++x) {
                const int d = 32 - f[x];
                if (role < 0 && r2 < cum + d) role = x * 32 + f[x] + (r2 - cum);
                cum += d;
            }
        }
        const int g = role >> 5;
        __hip_atomic_store(&ctl[32 + role], (int)xcc, __ATOMIC_RELAXED, __HIP_MEMORY_SCOPE_AGENT);
        __hip_atomic_fetch_add(&ctl[16 + g], 1, __ATOMIC_ACQ_REL, __HIP_MEMORY_SCOPE_AGENT);
        while (__hip_atomic_load(&ctl[16 + g], __ATOMIC_ACQUIRE, __HIP_MEMORY_SCOPE_AGENT) < 32)
            __builtin_amdgcn_s_sleep(8);
        int fast = 1;
        for (int k = 0; k < 32; ++k)
            if (__hip_atomic_load(&ctl[32 + g * 32 + k], __ATOMIC_RELAXED, __HIP_MEMORY_SCOPE_AGENT) != (int)xcc)
                fast = 0;
        sh_role = role;
        sh_fast = fast;
    }
    __syncthreads();
    const int role = sh_role;
    const int fastv = sh_fast;

    const int w = tid >> 6, l = tid & 63;
    const int jg = w >> 2;       // j half 0..1
    const int kw = w & 3;        // K-slice 0..3
    const int g = role >> 5;     // group = (dir, bh)
    const int jc = role & 31;    // 32 j-cols per block
    const int dir = g >> 2;
    const int bh = g & 3;
    const int lrow = l & 15;
    const int lhi = l >> 4;      // 0..3

    int* gflags = flags + g * 1024;   // 32 flags, stride 32 ints

    // w_hh fragments: rows = this block's 32 j-cols, K slice [kw*256,+256)
    const u16* wbase = WHH + (long)dir * 3072 * 1024;
    short8 breg[3][8];
#pragma unroll
    for (int nt = 0; nt < 3; ++nt) {
        const long row = nt * 1024 + jc * 32 + jg * 16 + lrow;
#pragma unroll
        for (int kk = 0; kk < 8; ++kk)
            breg[nt][kk] = *(const short8*)&wbase[row * 1024 + (kw * 8 + kk) * 32 + lhi * 8];
    }

    const int jd = jc * 32 + jg * 16 + lrow;     // j within dir (0..1023)
    const int jb = jc * 2 + jg;                  // 16-col group id
    const float bihR = bih[dir * 3072 + jd];
    const float bihZ = bih[dir * 3072 + 1024 + jd];
    const float bihN = bih[dir * 3072 + 2048 + jd];
    const float bhhR = bhh[dir * 3072 + jd];
    const float bhhZ = bhh[dir * 3072 + 1024 + jd];
    const float bhhN = bhh[dir * 3072 + 2048 + jd];

    // this thread's single output: b_loc = kw*4 + lhi, j = jd
    const int b_loc = kw * 4 + lhi;
    const int b_glob = bh * 16 + b_loc;
    float hreg = h0l[dir * 65536 + b_glob * 1024 + jd];

    const u16* gib = GIn + (long)(dir * 64 + jb) * 256 * 3072 + b_glob * 48 + lrow;

    // prologue: GI gate inputs for step 0
    u16 givR, givZ, givN;
    {
        const long toff = (long)(dir ? 255 : 0) * 3072;
        givR = __builtin_nontemporal_load(gib + toff);
        givZ = __builtin_nontemporal_load(gib + toff + 16);
        givN = __builtin_nontemporal_load(gib + toff + 32);
    }

#define LOADH(DST, KK)                                                          \
        {                                                                       \
            const u16* p = hb16 + lrow * 1024 + kw * 256 + (KK) * 32 + lhi * 8; \
            if constexpr (FAST) {                                               \
                DST = *(const short8*)p;                                        \
            } else {                                                            \
                const u64* q8 = (const u64*)p;                                  \
                u64x2 q;                                                        \
                q[0] = __hip_atomic_load(q8,     __ATOMIC_RELAXED, __HIP_MEMORY_SCOPE_AGENT); \
                q[1] = __hip_atomic_load(q8 + 1, __ATOMIC_RELAXED, __HIP_MEMORY_SCOPE_AGENT); \
                DST = __builtin_bit_cast(short8, q);                            \
            }                                                                   \
        }
#define MFMA3(SRC, KK)                                                          \
        {                                                                       \
            _Pragma("unroll")                                                   \
            for (int nt = 0; nt < 3; ++nt)                                      \
                acc[nt] = __builtin_amdgcn_mfma_f32_16x16x32_bf16(              \
                    SRC, breg[nt][KK], acc[nt], 0, 0, 0);                       \
        }

    auto body = [&](auto fc) {
        constexpr int FAST = decltype(fc)::v;
        for (int s = 0; s < 256; ++s) {
            const int parity = s & 1;
            const int t_eff = dir ? (255 - s) : s;
            if constexpr (FAST) {
                asm volatile("buffer_inv sc0" ::: "memory");   // L1 acquire
            }
            const u16* hb16 = H16G + (long)(parity * 8 + g) * 16384;

            short8 afX, afY, afZ, afW;
            floatx4 acc[3] = {};
            LOADH(afX, 0)
            LOADH(afY, 1)
            LOADH(afZ, 2)
            LOADH(afW, 3)

            // GI prefetch for NEXT step, issued during compute (R17 ordering)
            u16 gnR = 0, gnZ = 0, gnN = 0;
            if (s < 255) {
                const long toff = (long)(dir ? (254 - s) : (s + 1)) * 3072;
                gnR = __builtin_nontemporal_load(gib + toff);
                gnZ = __builtin_nontemporal_load(gib + toff + 16);
                gnN = __builtin_nontemporal_load(gib + toff + 32);
            }

            MFMA3(afX, 0) LOADH(afX, 4)
            MFMA3(afY, 1) LOADH(afY, 5)
            MFMA3(afZ, 2) LOADH(afZ, 6)
            MFMA3(afW, 3) LOADH(afW, 7)
            MFMA3(afX, 4)
            MFMA3(afY, 5)
            MFMA3(afZ, 6)
            MFMA3(afW, 7)

            // partials -> LDS: D row = b_local, col = j
#pragma unroll
            for (int nt = 0; nt < 3; ++nt)
                *(floatx4*)&P[jg][kw][0][nt][lrow][lhi * 4] = acc[nt];
            asm volatile("s_waitcnt lgkmcnt(0)" ::: "memory");
            __builtin_amdgcn_sched_barrier(0);
            __builtin_amdgcn_s_barrier();                  // B1: LDS only
            __builtin_amdgcn_sched_barrier(0);

            // reduce over kw partials for this thread's (j = jd, b = b_loc)
            float sR = 0.f, sZ = 0.f, sN = 0.f;
#pragma unroll
            for (int wp = 0; wp < 4; ++wp) {
                sR += P[jg][wp][0][0][lrow][b_loc];
                sZ += P[jg][wp][0][1][lrow][b_loc];
                sN += P[jg][wp][0][2][lrow][b_loc];
            }
            const float xr = bf2f(givR) + bihR + sR + bhhR;
            const float xz = bf2f(givZ) + bihZ + sZ + bhhZ;
            const float rg = 1.f / (1.f + __expf(-xr));
            const float zg = 1.f / (1.f + __expf(-xz));
            float xn = bf2f(givN) + bihN + rg * (sN + bhhN);
            xn = fminf(fmaxf(xn, -20.f), 20.f);
            const float e2 = __expf(-2.f * xn);
            const float ng = (1.f - e2) / (1.f + e2);
            const float hnew = (1.f - zg) * ng + zg * hreg;
            hreg = hnew;

            // stores: H16 first, then Y (both plain in FAST -> L2 ack)
            __builtin_amdgcn_sched_barrier(0);
            {
                u16* hp = H16G + (long)((parity ^ 1) * 8 + g) * 16384 + b_loc * 1024 + jd;
                if constexpr (FAST) *hp = f2bf(hnew);
                else __hip_atomic_store(hp, f2bf(hnew), __ATOMIC_RELAXED, __HIP_MEMORY_SCOPE_AGENT);
            }
            __builtin_amdgcn_sched_barrier(0);
            if (Yf32) {
                Yf32[(long)(t_eff * 64 + b_glob) * 2048 + dir * 1024 + jd] = hnew;
            } else {
                Ybf[((long)(dir * 64 + jb) * 256 + t_eff) * 1024 + b_glob * 16 + lrow] = f2bf(hnew);
            }
            __builtin_amdgcn_sched_barrier(0);
            asm volatile("s_waitcnt vmcnt(1)" ::: "memory");   // H16 acked
            __builtin_amdgcn_sched_barrier(0);
            __builtin_amdgcn_s_barrier();                  // B2: block's H16 visible
            if (tid == 0) {
                if constexpr (FAST) ((volatile int*)gflags)[jc * 32] = s + 1;
                else __hip_atomic_store(&gflags[jc * 32], s + 1, __ATOMIC_RELAXED, __HIP_MEMORY_SCOPE_AGENT);
            }

            // poll (wave 0 only; proven buffer_inv + volatile sequence)
            if (w == 0) {
                if constexpr (FAST) {
                    while (true) {
                        asm volatile("buffer_inv sc0" ::: "memory");
                        int v = ((volatile int*)gflags)[(l & 31) * 32];
                        if (v >= s + 1) break;
                        __builtin_amdgcn_s_sleep(1);
                    }
                } else {
                    while (__hip_atomic_load(&gflags[(l & 31) * 32], __ATOMIC_RELAXED, __HIP_MEMORY_SCOPE_AGENT) < s + 1)
                        __builtin_amdgcn_s_sleep(1);
                }
            }
            __builtin_amdgcn_sched_barrier(0);
            __builtin_amdgcn_s_barrier();                  // B3: release block
            __builtin_amdgcn_sched_barrier(0);

            givR = gnR; givZ = gnZ; givN = gnN;
        }
    };
    if (fastv) body(IC<1>{});
    else       body(IC<0>{});
#undef LOADH
#undef MFMA3
}

// ---------------- launch ------------------------------------------------------
extern "C" void kernel_launch(void* const* d_in, const int* in_sizes, int n_in,
                              void* d_out, int out_size, void* d_ws, size_t ws_size,
                              hipStream_t stream) {
    const float* x    = (const float*)d_in[0];
    const float* h0   = (const float*)d_in[1];
    const float* w_ih = (const float*)d_in[2];   // [3][2][3072][2048]
    const float* w_hh = (const float*)d_in[3];   // [3][2][3072][1024]
    const float* b_ih = (const float*)d_in[4];   // [3][2][3072]
    const float* b_hh = (const float*)d_in[5];
    float* out = (float*)d_out;

    char* ws = (char*)d_ws;
    u16*   XB0 = (u16*)(ws);                      //  64 MiB
    u16*   XB1 = (u16*)(ws + 67108864);           //  64 MiB
    u16*   GI  = (u16*)(ws + 134217728);          // 192 MiB scan-blocked bf16
    u16*   WIH = (u16*)(ws + 335544320);          //  24 MiB
    u16*   WHH = (u16*)(ws + 360710144);          //  12 MiB
    int*   SYNC = (int*)(ws + 373293056);         //  34 KiB flags+ctl (own region)
    u16*   H16 = (u16*)(ws + 374341632);          // 512 KiB group layout [2][8][16][1024]

    cvt_f32_bf16<<<16384, 256, 0, stream>>>(x, XB0, 33554432L);

    for (int layer = 0; layer < 3; ++layer) {
        const u16* xin = (layer == 1) ? XB1 : XB0;
        u16* yout = (layer == 0) ? XB1 : ((layer == 1) ? XB0 : nullptr);

        prep_layer<<<9762, 256, 0, stream>>>(w_ih + (long)layer * 12582912, WIH,
                                             w_hh + (long)layer * 6291456, WHH,
                                             h0 + (long)(2 * layer) * 65536, H16, SYNC);

        dim3 g(48, 128);
        if (layer == 0)
            gemm_bt_bf16<0><<<g, 256, 0, stream>>>(xin, WIH, GI);
        else
            gemm_bt_bf16<1><<<g, 256, 0, stream>>>(xin, WIH, GI);

        const float* bihl = b_ih + (long)layer * 6144;
        const float* bhhl = b_hh + (long)layer * 6144;
        gru_scan<<<256, 512, 0, stream>>>(WHH, GI, bihl, bhhl,
                                          h0 + (long)(2 * layer) * 65536, H16,
                                          yout, (layer == 2) ? out : nullptr, SYNC);
    }
}